// Round 16
// baseline (224.354 us; speedup 1.0000x reference)
//
#include <hip/hip_runtime.h>
#include <hip/hip_bf16.h>
#include <stdint.h>

// MHSA: B=4, N=8192, C=512, HEADS=8, d=64.
// R16: B streamed from global (L2-resident weights) into double-buffered
// registers; only A staged via global_load_lds->LDS. Rationale: R6/R9/R13
// all pinned at ~74us because the CU LDS pipe served ~88KB/block-step
// (A+B frag reads + DMA writes) ~= 1850 cyc/CU-step (85 B/cyc, m134) --
// the invariant wall. Removing B's 32KB reads + 8KB writes cuts LDS to
// ~48KB/block-step. Same R13 sync skeleton (vmcnt(0)+barrier certifies
// A-DMA(s+1) and B-glb(s+1)). LDS 3x16KB + 64KB epilogue, 2 blocks/CU.

typedef __bf16 bf16x8 __attribute__((ext_vector_type(8)));
typedef float f32x4 __attribute__((ext_vector_type(4)));

__device__ __forceinline__ unsigned short f2bf(float f) {
  unsigned u = __float_as_uint(f);
  u += 0x7fffu + ((u >> 16) & 1u);  // RNE
  return (unsigned short)(u >> 16);
}
__device__ __forceinline__ unsigned pk2(float a, float b) {
  return (unsigned)f2bf(a) | ((unsigned)f2bf(b) << 16);
}
__device__ __forceinline__ void unpk2(unsigned u, float& a, float& b) {
  a = __uint_as_float(u << 16);
  b = __uint_as_float(u & 0xffff0000u);
}
__device__ __forceinline__ void gload_lds16(const void* g, void* l) {
  __builtin_amdgcn_global_load_lds((const __attribute__((address_space(1))) void*)g,
                                   (__attribute__((address_space(3))) void*)l,
                                   16, 0, 0);
}

// ---------------- merged f32 -> bf16 convert (x, w_qkv, w_fc) ----------------
__global__ __launch_bounds__(256) void cvt_all(const float* __restrict__ x,
                                               const float* __restrict__ wq,
                                               const float* __restrict__ wf,
                                               unsigned short* __restrict__ xb,
                                               unsigned short* __restrict__ wqb,
                                               unsigned short* __restrict__ wfb) {
  const int n0 = 2097152;  // 32768*512/8
  const int n1 = 98304;    // 1536*512/8
  int i = blockIdx.x * 256 + threadIdx.x;
  const float* in;
  unsigned short* ob;
  int j;
  if (i < n0) {
    in = x; ob = xb; j = i;
  } else if (i < n0 + n1) {
    in = wq; ob = wqb; j = i - n0;
  } else {
    in = wf; ob = wfb; j = i - n0 - n1;
  }
  const float4* p = (const float4*)in;
  float4 a = p[j * 2];
  float4 b = p[j * 2 + 1];
  uint4 o;
  o.x = pk2(a.x, a.y);
  o.y = pk2(a.z, a.w);
  o.z = pk2(b.x, b.y);
  o.w = pk2(b.z, b.w);
  ((uint4*)ob)[j] = o;
}

// ---------------- 256x128 pipelined bf16 GEMM, C = A @ B^T + bias ----------------
// 8 waves (4M x 2N, wave-tile 64x64), 16x16x32 MFMA.
// A: 3 x 16 KiB LDS buffers (swizzled, DMA-staged). B: global->reg dbuf.
// A-region swizzle: phys(row,kg) = (row>>1)*128 + ((((row&1)<<2)|kg)^((row>>1)&7))*16.

#define STG_A(S, BUF)                                                                     \
  do {                                                                                    \
    int _k0 = (S) * 32;                                                                   \
    gload_lds16(Ag + (size_t)(bm0 + srowA0) * KDIM + _k0 + skofA0,                        \
                lds + (BUF) * 16384 + dstA0);                                             \
    gload_lds16(Ag + (size_t)(bm0 + srowA1) * KDIM + _k0 + skofA1,                        \
                lds + (BUF) * 16384 + dstA1);                                             \
  } while (0)

#define LOADB(S, RG)                                                                      \
  do {                                                                                    \
    RG[0] = *(const bf16x8*)(bbase + (S) * 32);                                           \
    RG[1] = *(const bf16x8*)(bbase + 16 * KDIM + (S) * 32);                               \
    RG[2] = *(const bf16x8*)(bbase + 32 * KDIM + (S) * 32);                               \
    RG[3] = *(const bf16x8*)(bbase + 48 * KDIM + (S) * 32);                               \
  } while (0)

#define STEP(S, BC, BN)                                                                   \
  do {                                                                                    \
    const int s_ = (S);                                                                   \
    asm volatile("s_waitcnt vmcnt(0)" ::: "memory"); /* A-DMA(s+1)+B(s+1) landed */       \
    __builtin_amdgcn_s_barrier();                    /* all waves certified */            \
    __builtin_amdgcn_sched_barrier(0);                                                    \
    if (s_ + 2 < NKT) STG_A(s_ + 2, (s_ + 2) % 3);                                        \
    if (s_ + 1 < NKT) LOADB(s_ + 1, BN);                                                  \
    const char* nab = lds + ((s_ + 1) % 3) * 16384 + wm * 4096 + pbase;                   \
    __builtin_amdgcn_s_setprio(1);                                                        \
    _Pragma("unroll") for (int _i = 0; _i < 4; ++_i) {                                    \
      acc[_i][0] = __builtin_amdgcn_mfma_f32_16x16x32_bf16(af[_i], BC[0], acc[_i][0], 0, 0, 0); \
      acc[_i][1] = __builtin_amdgcn_mfma_f32_16x16x32_bf16(af[_i], BC[1], acc[_i][1], 0, 0, 0); \
      acc[_i][2] = __builtin_amdgcn_mfma_f32_16x16x32_bf16(af[_i], BC[2], acc[_i][2], 0, 0, 0); \
      acc[_i][3] = __builtin_amdgcn_mfma_f32_16x16x32_bf16(af[_i], BC[3], acc[_i][3], 0, 0, 0); \
      if (s_ + 1 < NKT) af[_i] = *(const bf16x8*)(nab + _i * 1024);                       \
    }                                                                                     \
    __builtin_amdgcn_s_setprio(0);                                                        \
  } while (0)

template <bool OUT_BF16, int KDIM>
__global__ __launch_bounds__(512, 4) void gemmp(const __hip_bfloat16* __restrict__ Ag,
                                                const __hip_bfloat16* __restrict__ Bg,
                                                const float* __restrict__ bias,
                                                void* __restrict__ C,
                                                int M, int N, int NT) {
  __shared__ __align__(16) char lds[65536];  // 3x16KiB A pipeline; 64KiB epilogue

  const int tid = threadIdx.x;
  const int wv = tid >> 6;
  const int ln = tid & 63;
  const int lrow = ln & 15;
  const int kg = ln >> 4;
  const int wm = wv >> 1;  // 0..3 -> 64-row panel
  const int wn = wv & 1;   // 0..1 -> 64-col panel

  // XCD-aware bijective swizzle (gridDim.x % 8 == 0)
  int nwg = gridDim.x;
  int cpx = nwg >> 3;
  int bs = (blockIdx.x & 7) * cpx + (blockIdx.x >> 3);
  const int bm0 = (bs / NT) * 256;
  const int bn0 = (bs % NT) * 128;

  const int pbase = (lrow >> 1) * 128 + ((((lrow & 1) << 2) | kg) ^ ((lrow >> 1) & 7)) * 16;

  // A staging map (pre-swizzled global source, linear LDS dest)
  int srowA0, skofA0, dstA0, srowA1, skofA1, dstA1;
  {
    int L0 = wv * 1024 + ln * 16;
    int rp0 = L0 >> 7, T0 = ((L0 >> 4) & 7) ^ (rp0 & 7);
    srowA0 = rp0 * 2 + (T0 >> 2);
    skofA0 = (T0 & 3) * 8;
    dstA0 = wv * 1024;
    int L1 = 8192 + L0;
    int rp1 = L1 >> 7, T1 = ((L1 >> 4) & 7) ^ (rp1 & 7);
    srowA1 = rp1 * 2 + (T1 >> 2);
    skofA1 = (T1 & 3) * 8;
    dstA1 = 8192 + wv * 1024;
  }

  // per-lane B fragment base: row (bn0 + wn*64 + lrow), k-offset kg*8
  const __hip_bfloat16* bbase = Bg + (size_t)(bn0 + wn * 64 + lrow) * KDIM + kg * 8;

  f32x4 acc[4][4] = {};
  bf16x8 af[4], bs0[4], bs1[4];

  constexpr int NKT = KDIM >> 5;  // 16 for K=512

  // prologue: A(0) DMA, B(0) glb, A(1) DMA; certify A(0)+B(0)
  STG_A(0, 0);
  LOADB(0, bs0);
  STG_A(1, 1);
  asm volatile("s_waitcnt vmcnt(2)" ::: "memory");  // A(0)+B(0) landed; A(1) in flight
  __builtin_amdgcn_s_barrier();
  __builtin_amdgcn_sched_barrier(0);
  {
    const char* ab0 = lds + wm * 4096 + pbase;
#pragma unroll
    for (int i = 0; i < 4; ++i) af[i] = *(const bf16x8*)(ab0 + i * 1024);
  }

#pragma unroll
  for (int sp = 0; sp < NKT / 2; ++sp) {
    STEP(2 * sp, bs0, bs1);
    STEP(2 * sp + 1, bs1, bs0);
  }
  __syncthreads();  // all waves done with LDS; reusable for epilogue

  // ---- epilogue: LDS-shuffled coalesced writeout (R4-verified) ----
  if (OUT_BF16) {
    unsigned short* tile = (unsigned short*)lds;  // 256 x 128 bf16 = 64 KiB
#pragma unroll
    for (int fi = 0; fi < 4; ++fi) {
#pragma unroll
      for (int cj = 0; cj < 4; ++cj) {
        int col = wn * 64 + cj * 16 + lrow;
        float bv = bias[bn0 + col];
#pragma unroll
        for (int r = 0; r < 4; ++r) {
          int row = wm * 64 + fi * 16 + kg * 4 + r;
          int sc = (((col >> 3) ^ (row & 7)) << 3) | (col & 7);
          tile[row * 128 + sc] = f2bf(acc[fi][cj][r] + bv);
        }
      }
    }
    __syncthreads();
#pragma unroll
    for (int it = 0; it < 8; ++it) {
      int id = it * 512 + tid;
      int row = id >> 4;  // 0..255 ; 16 x 16B chunks/row
      int c = id & 15;
      uint4 v = *(const uint4*)(lds + row * 256 + ((c ^ (row & 7)) << 4));
      *(uint4*)((unsigned short*)C + (size_t)(bm0 + row) * N + bn0 + c * 8) = v;
    }
  } else {
    float* tilef = (float*)lds;  // 128 x 128 f32 = 64 KiB per pass
#pragma unroll
    for (int pass = 0; pass < 2; ++pass) {
      if ((wm >> 1) == pass) {
#pragma unroll
        for (int fi = 0; fi < 4; ++fi) {
#pragma unroll
          for (int cj = 0; cj < 4; ++cj) {
            int col = wn * 64 + cj * 16 + lrow;
            float bv = bias[bn0 + col];
#pragma unroll
            for (int r = 0; r < 4; ++r) {
              int row = (wm & 1) * 64 + fi * 16 + kg * 4 + r;  // 0..127
              int sc = (((col >> 2) ^ (row & 7)) << 2) | (col & 3);
              tilef[row * 128 + sc] = acc[fi][cj][r] + bv;
            }
          }
        }
      }
      __syncthreads();
#pragma unroll
      for (int it = 0; it < 8; ++it) {
        int id = it * 512 + tid;
        int row = id >> 5;  // 0..127 ; 32 x 16B chunks/row
        int c = id & 31;
        uint4 v = *(const uint4*)(lds + row * 512 + ((c ^ (row & 7)) << 4));
        *(uint4*)((float*)C + (size_t)(bm0 + pass * 128 + row) * N + bn0 + c * 4) = v;
      }
      __syncthreads();
    }
  }
}

// ---------------- per-token attention, 1 token per wave ----------------
__global__ __launch_bounds__(256) void attn_tok(const __hip_bfloat16* __restrict__ qkv,
                                                __hip_bfloat16* __restrict__ outp,
                                                int ntok, int npb) {
  const int wv = threadIdx.x >> 6;
  const int ln = threadIdx.x & 63;
  const int t = blockIdx.x * 4 + wv;
  if (t >= ntok) return;
  const int m = ln & 7;

  const __hip_bfloat16* row = qkv + (size_t)t * 1536;
  uint4 qr = *(const uint4*)(row + ln * 8);
  uint4 kr = *(const uint4*)(row + 512 + ln * 8);
  uint4 vr = *(const uint4*)(row + 1024 + ln * 8);

  float qf[8];
  unpk2(qr.x, qf[0], qf[1]);
  unpk2(qr.y, qf[2], qf[3]);
  unpk2(qr.z, qf[4], qf[5]);
  unpk2(qr.w, qf[6], qf[7]);
  unsigned kw[4] = {kr.x, kr.y, kr.z, kr.w};
  unsigned vw[4] = {vr.x, vr.y, vr.z, vr.w};

  float dt[8];
#pragma unroll
  for (int g = 0; g < 8; ++g) {
    int src = g * 8 + m;
    float s = 0.f;
#pragma unroll
    for (int j4 = 0; j4 < 4; ++j4) {
      unsigned kk = __shfl(kw[j4], src, 64);
      float a, b;
      unpk2(kk, a, b);
      s += qf[j4 * 2] * a + qf[j4 * 2 + 1] * b;
    }
    s += __shfl_xor(s, 1, 64);
    s += __shfl_xor(s, 2, 64);
    s += __shfl_xor(s, 4, 64);
    dt[g] = s;
  }

  float mx = -1e30f;
#pragma unroll
  for (int g = 0; g < 8; ++g) {
    dt[g] = fminf(fmaxf(dt[g] * 0.125f, -50.f), 50.f);
    mx = fmaxf(mx, dt[g]);
  }
  float p[8], ssum = 0.f;
#pragma unroll
  for (int g = 0; g < 8; ++g) {
    p[g] = __expf(dt[g] - mx);
    ssum += p[g];
  }
  float inv = 1.f / ssum;

  float o[8] = {0, 0, 0, 0, 0, 0, 0, 0};
#pragma unroll
  for (int g = 0; g < 8; ++g) {
    int src = g * 8 + m;
    float ag = p[g] * inv;
#pragma unroll
    for (int j4 = 0; j4 < 4; ++j4) {
      unsigned vv = __shfl(vw[j4], src, 64);
      float a, b;
      unpk2(vv, a, b);
      o[j4 * 2] += ag * a;
      o[j4 * 2 + 1] += ag * b;
    }
  }

  const int h = ln >> 3;
  const int b = t / npb, n = t % npb;
  size_t dst = (size_t)b * npb * 512 + (size_t)(h * (npb >> 3) + (n >> 3)) * 512 +
               (size_t)((n & 7) * 64 + m * 8);
  uint4 ov;
  ov.x = pk2(o[0], o[1]);
  ov.y = pk2(o[2], o[3]);
  ov.z = pk2(o[4], o[5]);
  ov.w = pk2(o[6], o[7]);
  *(uint4*)(outp + dst) = ov;
}

// ---------------- launch ----------------
extern "C" void kernel_launch(void* const* d_in, const int* in_sizes, int n_in,
                              void* d_out, int out_size, void* d_ws, size_t ws_size,
                              hipStream_t stream) {
  const float* x = (const float*)d_in[0];
  const float* w_qkv = (const float*)d_in[1];
  const float* b_qkv = (const float*)d_in[2];
  const float* w_fc = (const float*)d_in[3];
  const float* b_fc = (const float*)d_in[4];
  float* out = (float*)d_out;

  const int M = 32768;
  const int Cc = 512, N3 = 1536;

  __hip_bfloat16* xb = (__hip_bfloat16*)d_ws;
  __hip_bfloat16* wqkvb = xb + (size_t)M * Cc;
  __hip_bfloat16* wfcb = wqkvb + (size_t)N3 * Cc;
  __hip_bfloat16* qkvb = wfcb + (size_t)Cc * Cc;
  __hip_bfloat16* attb = qkvb + (size_t)M * N3;

  cvt_all<<<8704, 256, 0, stream>>>(x, w_qkv, w_fc, (unsigned short*)xb,
                                    (unsigned short*)wqkvb, (unsigned short*)wfcb);

  gemmp<true, 512><<<(M / 256) * (N3 / 128), 512, 0, stream>>>(xb, wqkvb, b_qkv, qkvb, M, N3,
                                                               N3 / 128);
  attn_tok<<<M / 4, 256, 0, stream>>>(qkvb, attb, M, 8192);
  gemmp<false, 512><<<(M / 256) * (Cc / 128), 512, 0, stream>>>(attb, wfcb, b_fc, out, M, Cc,
                                                                Cc / 128);
}

// Round 17
// 150.430 us; speedup vs baseline: 1.4914x; 1.4914x over previous
//
#include <hip/hip_runtime.h>
#include <hip/hip_bf16.h>
#include <stdint.h>

// MHSA: B=4, N=8192, C=512, HEADS=8, d=64.
// R17: R13 restored (best: 146.4us) + FC restructured: 128x128 tile, 4 waves,
// BK=32, 2x16KiB LDS depth-1 schedule -> 4 blocks/CU (4 independent barrier
// domains at the same 16 waves/CU). QKV is at its structure ceiling (~74us,
// 696 TF > m233's 2-barrier ceiling; 8-phase needs K-depth K=512 lacks).

typedef __bf16 bf16x8 __attribute__((ext_vector_type(8)));
typedef float f32x4 __attribute__((ext_vector_type(4)));

__device__ __forceinline__ unsigned short f2bf(float f) {
  unsigned u = __float_as_uint(f);
  u += 0x7fffu + ((u >> 16) & 1u);  // RNE
  return (unsigned short)(u >> 16);
}
__device__ __forceinline__ unsigned pk2(float a, float b) {
  return (unsigned)f2bf(a) | ((unsigned)f2bf(b) << 16);
}
__device__ __forceinline__ void unpk2(unsigned u, float& a, float& b) {
  a = __uint_as_float(u << 16);
  b = __uint_as_float(u & 0xffff0000u);
}
__device__ __forceinline__ void gload_lds16(const void* g, void* l) {
  __builtin_amdgcn_global_load_lds((const __attribute__((address_space(1))) void*)g,
                                   (__attribute__((address_space(3))) void*)l,
                                   16, 0, 0);
}

// ---------------- merged f32 -> bf16 convert ----------------
__global__ __launch_bounds__(256) void cvt_all(const float* __restrict__ x,
                                               const float* __restrict__ wq,
                                               const float* __restrict__ wf,
                                               unsigned short* __restrict__ xb,
                                               unsigned short* __restrict__ wqb,
                                               unsigned short* __restrict__ wfb) {
  const int n0 = 2097152;  // 32768*512/8
  const int n1 = 98304;    // 1536*512/8
  int i = blockIdx.x * 256 + threadIdx.x;
  const float* in;
  unsigned short* ob;
  int j;
  if (i < n0) {
    in = x; ob = xb; j = i;
  } else if (i < n0 + n1) {
    in = wq; ob = wqb; j = i - n0;
  } else {
    in = wf; ob = wfb; j = i - n0 - n1;
  }
  const float4* p = (const float4*)in;
  float4 a = p[j * 2];
  float4 b = p[j * 2 + 1];
  uint4 o;
  o.x = pk2(a.x, a.y);
  o.y = pk2(a.z, a.w);
  o.z = pk2(b.x, b.y);
  o.w = pk2(b.z, b.w);
  ((uint4*)ob)[j] = o;
}

// ================= QKV GEMM: R13 verbatim (256x128, 8 waves, 3-buf) =================
#define STG(S, BUF)                                                                       \
  do {                                                                                    \
    int _k0 = (S) * 32;                                                                   \
    gload_lds16(Ag + (size_t)(bm0 + srowA0) * KDIM + _k0 + skofA0,                        \
                lds + (BUF) * 24576 + dstA0);                                             \
    gload_lds16(Ag + (size_t)(bm0 + srowA1) * KDIM + _k0 + skofA1,                        \
                lds + (BUF) * 24576 + dstA1);                                             \
    gload_lds16(Bg + (size_t)(bn0 + srowB) * KDIM + _k0 + skofB,                          \
                lds + (BUF) * 24576 + 16384 + dstB);                                      \
  } while (0)

#define STEP(S, BC, BN)                                                                   \
  do {                                                                                    \
    const int s_ = (S);                                                                   \
    asm volatile("s_waitcnt vmcnt(0)" ::: "memory");                                      \
    __builtin_amdgcn_s_barrier();                                                         \
    __builtin_amdgcn_sched_barrier(0);                                                    \
    if (s_ + 2 < NKT) STG(s_ + 2, (s_ + 2) % 3);                                          \
    const char* nab = lds + ((s_ + 1) % 3) * 24576 + wm * 4096 + pbase;                   \
    const char* nbb = lds + ((s_ + 1) % 3) * 24576 + 16384 + wn * 4096 + pbase;           \
    if (s_ + 1 < NKT) {                                                                   \
      BN[0] = *(const bf16x8*)(nbb);                                                      \
      BN[1] = *(const bf16x8*)(nbb + 1024);                                               \
      BN[2] = *(const bf16x8*)(nbb + 2048);                                               \
      BN[3] = *(const bf16x8*)(nbb + 3072);                                               \
    }                                                                                     \
    __builtin_amdgcn_s_setprio(1);                                                        \
    _Pragma("unroll") for (int _i = 0; _i < 4; ++_i) {                                    \
      acc[_i][0] = __builtin_amdgcn_mfma_f32_16x16x32_bf16(af[_i], BC[0], acc[_i][0], 0, 0, 0); \
      acc[_i][1] = __builtin_amdgcn_mfma_f32_16x16x32_bf16(af[_i], BC[1], acc[_i][1], 0, 0, 0); \
      acc[_i][2] = __builtin_amdgcn_mfma_f32_16x16x32_bf16(af[_i], BC[2], acc[_i][2], 0, 0, 0); \
      acc[_i][3] = __builtin_amdgcn_mfma_f32_16x16x32_bf16(af[_i], BC[3], acc[_i][3], 0, 0, 0); \
      if (s_ + 1 < NKT) af[_i] = *(const bf16x8*)(nab + _i * 1024);                       \
    }                                                                                     \
    __builtin_amdgcn_s_setprio(0);                                                        \
  } while (0)

template <int KDIM>
__global__ __launch_bounds__(512, 4) void gemm_qkv(const __hip_bfloat16* __restrict__ Ag,
                                                   const __hip_bfloat16* __restrict__ Bg,
                                                   const float* __restrict__ bias,
                                                   void* __restrict__ C,
                                                   int M, int N, int NT) {
  __shared__ __align__(16) char lds[73728];

  const int tid = threadIdx.x;
  const int wv = tid >> 6;
  const int ln = tid & 63;
  const int lrow = ln & 15;
  const int kg = ln >> 4;
  const int wm = wv >> 1;
  const int wn = wv & 1;

  int nwg = gridDim.x;
  int cpx = nwg >> 3;
  int bs = (blockIdx.x & 7) * cpx + (blockIdx.x >> 3);
  const int bm0 = (bs / NT) * 256;
  const int bn0 = (bs % NT) * 128;

  const int pbase = (lrow >> 1) * 128 + ((((lrow & 1) << 2) | kg) ^ ((lrow >> 1) & 7)) * 16;

  int srowA0, skofA0, dstA0, srowA1, skofA1, dstA1, srowB, skofB, dstB;
  {
    int L0 = wv * 1024 + ln * 16;
    int rp0 = L0 >> 7, T0 = ((L0 >> 4) & 7) ^ (rp0 & 7);
    srowA0 = rp0 * 2 + (T0 >> 2);
    skofA0 = (T0 & 3) * 8;
    dstA0 = wv * 1024;
    int L1 = 8192 + L0;
    int rp1 = L1 >> 7, T1 = ((L1 >> 4) & 7) ^ (rp1 & 7);
    srowA1 = rp1 * 2 + (T1 >> 2);
    skofA1 = (T1 & 3) * 8;
    dstA1 = 8192 + wv * 1024;
    srowB = srowA0;
    skofB = skofA0;
    dstB = wv * 1024;
  }

  f32x4 acc[4][4] = {};
  bf16x8 af[4], bs0[4], bs1[4];

  constexpr int NKT = KDIM >> 5;

  STG(0, 0);
  STG(1, 1);
  asm volatile("s_waitcnt vmcnt(3)" ::: "memory");
  __builtin_amdgcn_s_barrier();
  __builtin_amdgcn_sched_barrier(0);
  {
    const char* ab0 = lds + wm * 4096 + pbase;
    const char* bb0 = lds + 16384 + wn * 4096 + pbase;
#pragma unroll
    for (int i = 0; i < 4; ++i) af[i] = *(const bf16x8*)(ab0 + i * 1024);
#pragma unroll
    for (int j = 0; j < 4; ++j) bs0[j] = *(const bf16x8*)(bb0 + j * 1024);
  }

#pragma unroll
  for (int sp = 0; sp < NKT / 2; ++sp) {
    STEP(2 * sp, bs0, bs1);
    STEP(2 * sp + 1, bs1, bs0);
  }
  __syncthreads();

  // bf16 epilogue (R4-verified)
  unsigned short* tile = (unsigned short*)lds;
#pragma unroll
  for (int fi = 0; fi < 4; ++fi) {
#pragma unroll
    for (int cj = 0; cj < 4; ++cj) {
      int col = wn * 64 + cj * 16 + lrow;
      float bv = bias[bn0 + col];
#pragma unroll
      for (int r = 0; r < 4; ++r) {
        int row = wm * 64 + fi * 16 + kg * 4 + r;
        int sc = (((col >> 3) ^ (row & 7)) << 3) | (col & 7);
        tile[row * 128 + sc] = f2bf(acc[fi][cj][r] + bv);
      }
    }
  }
  __syncthreads();
#pragma unroll
  for (int it = 0; it < 8; ++it) {
    int id = it * 512 + tid;
    int row = id >> 4;
    int c = id & 15;
    uint4 v = *(const uint4*)(lds + row * 256 + ((c ^ (row & 7)) << 4));
    *(uint4*)((unsigned short*)C + (size_t)(bm0 + row) * N + bn0 + c * 8) = v;
  }
}

// ================= FC GEMM: 128x128, 4 waves, BK=32, 2-buf depth-1 =================
#define FSTG(S, BUF)                                                                      \
  do {                                                                                    \
    int _k0 = (S) * 32;                                                                   \
    gload_lds16(Ag + (size_t)(bm0 + srowA0) * KDIM + _k0 + skofA0,                        \
                lds + (BUF) * 16384 + dstA0);                                             \
    gload_lds16(Ag + (size_t)(bm0 + srowA1) * KDIM + _k0 + skofA1,                        \
                lds + (BUF) * 16384 + dstA1);                                             \
    gload_lds16(Bg + (size_t)(bn0 + srowB0) * KDIM + _k0 + skofB0,                        \
                lds + (BUF) * 16384 + 8192 + dstB0);                                      \
    gload_lds16(Bg + (size_t)(bn0 + srowB1) * KDIM + _k0 + skofB1,                        \
                lds + (BUF) * 16384 + 8192 + dstB1);                                      \
  } while (0)

template <int KDIM>
__global__ __launch_bounds__(256, 4) void gemm_fc(const __hip_bfloat16* __restrict__ Ag,
                                                  const __hip_bfloat16* __restrict__ Bg,
                                                  const float* __restrict__ bias,
                                                  float* __restrict__ C,
                                                  int M, int N, int NT) {
  __shared__ __align__(16) char lds[32768];  // 2 x 16 KiB; epilogue reuses 32 KiB

  const int tid = threadIdx.x;
  const int wv = tid >> 6;
  const int ln = tid & 63;
  const int lrow = ln & 15;
  const int kg = ln >> 4;
  const int wm = wv >> 1;  // 0..1 -> 64-row panel
  const int wn = wv & 1;   // 0..1 -> 64-col panel

  int nwg = gridDim.x;
  int cpx = nwg >> 3;
  int bs = (blockIdx.x & 7) * cpx + (blockIdx.x >> 3);
  const int bm0 = (bs / NT) * 128;
  const int bn0 = (bs % NT) * 128;

  const int pbase = (lrow >> 1) * 128 + ((((lrow & 1) << 2) | kg) ^ ((lrow >> 1) & 7)) * 16;

  // staging: regions are 8 KiB (128 rows x 32k); 2 issues per region, 4 waves x 1 KiB
  int srowA0, skofA0, dstA0, srowA1, skofA1, dstA1;
  int srowB0, skofB0, dstB0, srowB1, skofB1, dstB1;
  {
    int L0 = wv * 1024 + ln * 16;
    int rp0 = L0 >> 7, T0 = ((L0 >> 4) & 7) ^ (rp0 & 7);
    srowA0 = rp0 * 2 + (T0 >> 2);
    skofA0 = (T0 & 3) * 8;
    dstA0 = wv * 1024;
    int L1 = 4096 + L0;
    int rp1 = L1 >> 7, T1 = ((L1 >> 4) & 7) ^ (rp1 & 7);
    srowA1 = rp1 * 2 + (T1 >> 2);
    skofA1 = (T1 & 3) * 8;
    dstA1 = 4096 + wv * 1024;
    srowB0 = srowA0; skofB0 = skofA0; dstB0 = dstA0;
    srowB1 = srowA1; skofB1 = skofA1; dstB1 = dstA1;
  }

  f32x4 acc[4][4] = {};

  constexpr int NKT = KDIM >> 5;  // 16

  FSTG(0, 0);
  asm volatile("s_waitcnt vmcnt(0)" ::: "memory");
  __builtin_amdgcn_s_barrier();
  __builtin_amdgcn_sched_barrier(0);

#pragma unroll
  for (int s = 0; s < NKT; ++s) {
    int b = s & 1;
    if (s + 1 < NKT) FSTG(s + 1, b ^ 1);
    {
      const char* ab = lds + b * 16384 + wm * 4096 + pbase;
      const char* bb = lds + b * 16384 + 8192 + wn * 4096 + pbase;
      bf16x8 a0 = *(const bf16x8*)(ab);
      bf16x8 a1 = *(const bf16x8*)(ab + 1024);
      bf16x8 a2 = *(const bf16x8*)(ab + 2048);
      bf16x8 a3 = *(const bf16x8*)(ab + 3072);
      bf16x8 b0 = *(const bf16x8*)(bb);
      bf16x8 b1 = *(const bf16x8*)(bb + 1024);
      bf16x8 b2 = *(const bf16x8*)(bb + 2048);
      bf16x8 b3 = *(const bf16x8*)(bb + 3072);
      asm volatile("s_waitcnt lgkmcnt(0)" ::: "memory");
      __builtin_amdgcn_sched_barrier(0);
      __builtin_amdgcn_s_setprio(1);
      acc[0][0] = __builtin_amdgcn_mfma_f32_16x16x32_bf16(a0, b0, acc[0][0], 0, 0, 0);
      acc[0][1] = __builtin_amdgcn_mfma_f32_16x16x32_bf16(a0, b1, acc[0][1], 0, 0, 0);
      acc[0][2] = __builtin_amdgcn_mfma_f32_16x16x32_bf16(a0, b2, acc[0][2], 0, 0, 0);
      acc[0][3] = __builtin_amdgcn_mfma_f32_16x16x32_bf16(a0, b3, acc[0][3], 0, 0, 0);
      acc[1][0] = __builtin_amdgcn_mfma_f32_16x16x32_bf16(a1, b0, acc[1][0], 0, 0, 0);
      acc[1][1] = __builtin_amdgcn_mfma_f32_16x16x32_bf16(a1, b1, acc[1][1], 0, 0, 0);
      acc[1][2] = __builtin_amdgcn_mfma_f32_16x16x32_bf16(a1, b2, acc[1][2], 0, 0, 0);
      acc[1][3] = __builtin_amdgcn_mfma_f32_16x16x32_bf16(a1, b3, acc[1][3], 0, 0, 0);
      acc[2][0] = __builtin_amdgcn_mfma_f32_16x16x32_bf16(a2, b0, acc[2][0], 0, 0, 0);
      acc[2][1] = __builtin_amdgcn_mfma_f32_16x16x32_bf16(a2, b1, acc[2][1], 0, 0, 0);
      acc[2][2] = __builtin_amdgcn_mfma_f32_16x16x32_bf16(a2, b2, acc[2][2], 0, 0, 0);
      acc[2][3] = __builtin_amdgcn_mfma_f32_16x16x32_bf16(a2, b3, acc[2][3], 0, 0, 0);
      acc[3][0] = __builtin_amdgcn_mfma_f32_16x16x32_bf16(a3, b0, acc[3][0], 0, 0, 0);
      acc[3][1] = __builtin_amdgcn_mfma_f32_16x16x32_bf16(a3, b1, acc[3][1], 0, 0, 0);
      acc[3][2] = __builtin_amdgcn_mfma_f32_16x16x32_bf16(a3, b2, acc[3][2], 0, 0, 0);
      acc[3][3] = __builtin_amdgcn_mfma_f32_16x16x32_bf16(a3, b3, acc[3][3], 0, 0, 0);
      __builtin_amdgcn_s_setprio(0);
    }
    asm volatile("s_waitcnt vmcnt(0)" ::: "memory");
    __builtin_amdgcn_s_barrier();
    __builtin_amdgcn_sched_barrier(0);
  }
  __syncthreads();

  // f32 epilogue: 2 passes of 64 rows (32 KiB each), XOR-swizzled tile
  float* tilef = (float*)lds;
#pragma unroll
  for (int pass = 0; pass < 2; ++pass) {
    if (wm == pass) {
#pragma unroll
      for (int fi = 0; fi < 4; ++fi) {
#pragma unroll
        for (int cj = 0; cj < 4; ++cj) {
          int col = wn * 64 + cj * 16 + lrow;
          float bv = bias[bn0 + col];
#pragma unroll
          for (int r = 0; r < 4; ++r) {
            int row = fi * 16 + kg * 4 + r;  // 0..63
            int sc = (((col >> 2) ^ (row & 7)) << 2) | (col & 3);
            tilef[row * 128 + sc] = acc[fi][cj][r] + bv;
          }
        }
      }
    }
    __syncthreads();
#pragma unroll
    for (int it = 0; it < 8; ++it) {
      int id = it * 256 + tid;
      int row = id >> 5;  // 0..63 ; 32 x 16B chunks/row
      int c = id & 31;
      uint4 v = *(const uint4*)(lds + row * 512 + ((c ^ (row & 7)) << 4));
      *(uint4*)(C + (size_t)(bm0 + pass * 64 + row) * N + bn0 + c * 4) = v;
    }
    __syncthreads();
  }
}

// ---------------- per-token attention, 1 token per wave ----------------
__global__ __launch_bounds__(256) void attn_tok(const __hip_bfloat16* __restrict__ qkv,
                                                __hip_bfloat16* __restrict__ outp,
                                                int ntok, int npb) {
  const int wv = threadIdx.x >> 6;
  const int ln = threadIdx.x & 63;
  const int t = blockIdx.x * 4 + wv;
  if (t >= ntok) return;
  const int m = ln & 7;

  const __hip_bfloat16* row = qkv + (size_t)t * 1536;
  uint4 qr = *(const uint4*)(row + ln * 8);
  uint4 kr = *(const uint4*)(row + 512 + ln * 8);
  uint4 vr = *(const uint4*)(row + 1024 + ln * 8);

  float qf[8];
  unpk2(qr.x, qf[0], qf[1]);
  unpk2(qr.y, qf[2], qf[3]);
  unpk2(qr.z, qf[4], qf[5]);
  unpk2(qr.w, qf[6], qf[7]);
  unsigned kw[4] = {kr.x, kr.y, kr.z, kr.w};
  unsigned vw[4] = {vr.x, vr.y, vr.z, vr.w};

  float dt[8];
#pragma unroll
  for (int g = 0; g < 8; ++g) {
    int src = g * 8 + m;
    float s = 0.f;
#pragma unroll
    for (int j4 = 0; j4 < 4; ++j4) {
      unsigned kk = __shfl(kw[j4], src, 64);
      float a, b;
      unpk2(kk, a, b);
      s += qf[j4 * 2] * a + qf[j4 * 2 + 1] * b;
    }
    s += __shfl_xor(s, 1, 64);
    s += __shfl_xor(s, 2, 64);
    s += __shfl_xor(s, 4, 64);
    dt[g] = s;
  }

  float mx = -1e30f;
#pragma unroll
  for (int g = 0; g < 8; ++g) {
    dt[g] = fminf(fmaxf(dt[g] * 0.125f, -50.f), 50.f);
    mx = fmaxf(mx, dt[g]);
  }
  float p[8], ssum = 0.f;
#pragma unroll
  for (int g = 0; g < 8; ++g) {
    p[g] = __expf(dt[g] - mx);
    ssum += p[g];
  }
  float inv = 1.f / ssum;

  float o[8] = {0, 0, 0, 0, 0, 0, 0, 0};
#pragma unroll
  for (int g = 0; g < 8; ++g) {
    int src = g * 8 + m;
    float ag = p[g] * inv;
#pragma unroll
    for (int j4 = 0; j4 < 4; ++j4) {
      unsigned vv = __shfl(vw[j4], src, 64);
      float a, b;
      unpk2(vv, a, b);
      o[j4 * 2] += ag * a;
      o[j4 * 2 + 1] += ag * b;
    }
  }

  const int h = ln >> 3;
  const int b = t / npb, n = t % npb;
  size_t dst = (size_t)b * npb * 512 + (size_t)(h * (npb >> 3) + (n >> 3)) * 512 +
               (size_t)((n & 7) * 64 + m * 8);
  uint4 ov;
  ov.x = pk2(o[0], o[1]);
  ov.y = pk2(o[2], o[3]);
  ov.z = pk2(o[4], o[5]);
  ov.w = pk2(o[6], o[7]);
  *(uint4*)(outp + dst) = ov;
}

// ---------------- launch ----------------
extern "C" void kernel_launch(void* const* d_in, const int* in_sizes, int n_in,
                              void* d_out, int out_size, void* d_ws, size_t ws_size,
                              hipStream_t stream) {
  const float* x = (const float*)d_in[0];
  const float* w_qkv = (const float*)d_in[1];
  const float* b_qkv = (const float*)d_in[2];
  const float* w_fc = (const float*)d_in[3];
  const float* b_fc = (const float*)d_in[4];
  float* out = (float*)d_out;

  const int M = 32768;
  const int Cc = 512, N3 = 1536;

  __hip_bfloat16* xb = (__hip_bfloat16*)d_ws;
  __hip_bfloat16* wqkvb = xb + (size_t)M * Cc;
  __hip_bfloat16* wfcb = wqkvb + (size_t)N3 * Cc;
  __hip_bfloat16* qkvb = wfcb + (size_t)Cc * Cc;
  __hip_bfloat16* attb = qkvb + (size_t)M * N3;

  cvt_all<<<8704, 256, 0, stream>>>(x, w_qkv, w_fc, (unsigned short*)xb,
                                    (unsigned short*)wqkvb, (unsigned short*)wfcb);

  // QKV: 128 x 12 = 1536 blocks (256x128 tile, 8 waves)
  gemm_qkv<512><<<(M / 256) * (N3 / 128), 512, 0, stream>>>(xb, wqkvb, b_qkv, qkvb, M, N3,
                                                            N3 / 128);
  attn_tok<<<M / 4, 256, 0, stream>>>(qkvb, attb, M, 8192);
  // FC: 256 x 4 = 1024 blocks (128x128 tile, 4 waves, 4 blocks/CU)
  gemm_fc<512><<<(M / 128) * (Cc / 128), 256, 0, stream>>>(attb, wfcb, b_fc, out, M, Cc,
                                                           Cc / 128);
}

// Round 18
// 146.153 us; speedup vs baseline: 1.5351x; 1.0293x over previous
//
#include <hip/hip_runtime.h>
#include <hip/hip_bf16.h>
#include <stdint.h>

// MHSA: B=4, N=8192, C=512, HEADS=8, d=64.
// R18 = R13 (best measured: 146.4 us). QKV GEMM at its structural ceiling
// (~700 TF for the 2-barrier-class schedule at K=512; 9 schedule variants
// all land 73.5-74.7 us — MfmaUtil 30%, HBM 24%, no pipe saturated; the
// per-K-step barrier serial structure is the invariant). cvt/attn/FC near
// memory floors. Pipeline: cvt_all -> gemm(QKV,bf16 out) -> attn_tok ->
// gemm(FC,f32 out). GEMM: 256x128 tile, 8 waves, 3x24KiB LDS, depth-2
// counted-vmcnt software-pipelined frag reads, XOR-swizzled staging +
// LDS-shuffled coalesced epilogue.

typedef __bf16 bf16x8 __attribute__((ext_vector_type(8)));
typedef float f32x4 __attribute__((ext_vector_type(4)));

__device__ __forceinline__ unsigned short f2bf(float f) {
  unsigned u = __float_as_uint(f);
  u += 0x7fffu + ((u >> 16) & 1u);  // RNE
  return (unsigned short)(u >> 16);
}
__device__ __forceinline__ unsigned pk2(float a, float b) {
  return (unsigned)f2bf(a) | ((unsigned)f2bf(b) << 16);
}
__device__ __forceinline__ void unpk2(unsigned u, float& a, float& b) {
  a = __uint_as_float(u << 16);
  b = __uint_as_float(u & 0xffff0000u);
}
__device__ __forceinline__ void gload_lds16(const void* g, void* l) {
  __builtin_amdgcn_global_load_lds((const __attribute__((address_space(1))) void*)g,
                                   (__attribute__((address_space(3))) void*)l,
                                   16, 0, 0);
}

// ---------------- merged f32 -> bf16 convert ----------------
__global__ __launch_bounds__(256) void cvt_all(const float* __restrict__ x,
                                               const float* __restrict__ wq,
                                               const float* __restrict__ wf,
                                               unsigned short* __restrict__ xb,
                                               unsigned short* __restrict__ wqb,
                                               unsigned short* __restrict__ wfb) {
  const int n0 = 2097152;  // 32768*512/8
  const int n1 = 98304;    // 1536*512/8
  int i = blockIdx.x * 256 + threadIdx.x;
  const float* in;
  unsigned short* ob;
  int j;
  if (i < n0) {
    in = x; ob = xb; j = i;
  } else if (i < n0 + n1) {
    in = wq; ob = wqb; j = i - n0;
  } else {
    in = wf; ob = wfb; j = i - n0 - n1;
  }
  const float4* p = (const float4*)in;
  float4 a = p[j * 2];
  float4 b = p[j * 2 + 1];
  uint4 o;
  o.x = pk2(a.x, a.y);
  o.y = pk2(a.z, a.w);
  o.z = pk2(b.x, b.y);
  o.w = pk2(b.z, b.w);
  ((uint4*)ob)[j] = o;
}

// ---------------- 256x128 pipelined bf16 GEMM, C = A @ B^T + bias ----------------
// 8 waves (4M x 2N, wave-tile 64x64), 16x16x32 MFMA, 3 x 24 KiB LDS buffers.
// Region swizzle: phys(row,kg) = (row>>1)*128 + ((((row&1)<<2)|kg)^((row>>1)&7))*16.

#define STG(S, BUF)                                                                       \
  do {                                                                                    \
    int _k0 = (S) * 32;                                                                   \
    gload_lds16(Ag + (size_t)(bm0 + srowA0) * KDIM + _k0 + skofA0,                        \
                lds + (BUF) * 24576 + dstA0);                                             \
    gload_lds16(Ag + (size_t)(bm0 + srowA1) * KDIM + _k0 + skofA1,                        \
                lds + (BUF) * 24576 + dstA1);                                             \
    gload_lds16(Bg + (size_t)(bn0 + srowB) * KDIM + _k0 + skofB,                          \
                lds + (BUF) * 24576 + 16384 + dstB);                                      \
  } while (0)

#define STEP(S, BC, BN)                                                                   \
  do {                                                                                    \
    const int s_ = (S);                                                                   \
    asm volatile("s_waitcnt vmcnt(0)" ::: "memory"); /* own STG(s+1) landed */            \
    __builtin_amdgcn_s_barrier();                    /* all waves certified */            \
    __builtin_amdgcn_sched_barrier(0);                                                    \
    if (s_ + 2 < NKT) STG(s_ + 2, (s_ + 2) % 3);                                          \
    const char* nab = lds + ((s_ + 1) % 3) * 24576 + wm * 4096 + pbase;                   \
    const char* nbb = lds + ((s_ + 1) % 3) * 24576 + 16384 + wn * 4096 + pbase;           \
    if (s_ + 1 < NKT) {                                                                   \
      BN[0] = *(const bf16x8*)(nbb);                                                      \
      BN[1] = *(const bf16x8*)(nbb + 1024);                                               \
      BN[2] = *(const bf16x8*)(nbb + 2048);                                               \
      BN[3] = *(const bf16x8*)(nbb + 3072);                                               \
    }                                                                                     \
    __builtin_amdgcn_s_setprio(1);                                                        \
    _Pragma("unroll") for (int _i = 0; _i < 4; ++_i) {                                    \
      acc[_i][0] = __builtin_amdgcn_mfma_f32_16x16x32_bf16(af[_i], BC[0], acc[_i][0], 0, 0, 0); \
      acc[_i][1] = __builtin_amdgcn_mfma_f32_16x16x32_bf16(af[_i], BC[1], acc[_i][1], 0, 0, 0); \
      acc[_i][2] = __builtin_amdgcn_mfma_f32_16x16x32_bf16(af[_i], BC[2], acc[_i][2], 0, 0, 0); \
      acc[_i][3] = __builtin_amdgcn_mfma_f32_16x16x32_bf16(af[_i], BC[3], acc[_i][3], 0, 0, 0); \
      if (s_ + 1 < NKT) af[_i] = *(const bf16x8*)(nab + _i * 1024);                       \
    }                                                                                     \
    __builtin_amdgcn_s_setprio(0);                                                        \
  } while (0)

template <bool OUT_BF16, int KDIM>
__global__ __launch_bounds__(512, 4) void gemmp(const __hip_bfloat16* __restrict__ Ag,
                                                const __hip_bfloat16* __restrict__ Bg,
                                                const float* __restrict__ bias,
                                                void* __restrict__ C,
                                                int M, int N, int NT) {
  __shared__ __align__(16) char lds[73728];

  const int tid = threadIdx.x;
  const int wv = tid >> 6;
  const int ln = tid & 63;
  const int lrow = ln & 15;
  const int kg = ln >> 4;
  const int wm = wv >> 1;  // 0..3 -> 64-row panel
  const int wn = wv & 1;   // 0..1 -> 64-col panel

  // XCD-aware bijective swizzle (gridDim.x % 8 == 0)
  int nwg = gridDim.x;
  int cpx = nwg >> 3;
  int bs = (blockIdx.x & 7) * cpx + (blockIdx.x >> 3);
  const int bm0 = (bs / NT) * 256;
  const int bn0 = (bs % NT) * 128;

  const int pbase = (lrow >> 1) * 128 + ((((lrow & 1) << 2) | kg) ^ ((lrow >> 1) & 7)) * 16;

  // staging maps (pre-swizzled global source, linear LDS dest)
  int srowA0, skofA0, dstA0, srowA1, skofA1, dstA1, srowB, skofB, dstB;
  {
    int L0 = wv * 1024 + ln * 16;
    int rp0 = L0 >> 7, T0 = ((L0 >> 4) & 7) ^ (rp0 & 7);
    srowA0 = rp0 * 2 + (T0 >> 2);
    skofA0 = (T0 & 3) * 8;
    dstA0 = wv * 1024;
    int L1 = 8192 + L0;
    int rp1 = L1 >> 7, T1 = ((L1 >> 4) & 7) ^ (rp1 & 7);
    srowA1 = rp1 * 2 + (T1 >> 2);
    skofA1 = (T1 & 3) * 8;
    dstA1 = 8192 + wv * 1024;
    srowB = srowA0;
    skofB = skofA0;
    dstB = wv * 1024;
  }

  f32x4 acc[4][4] = {};
  bf16x8 af[4], bs0[4], bs1[4];

  constexpr int NKT = KDIM >> 5;  // 16 for K=512

  // prologue: stage tiles 0,1; certify tile 0 everywhere; read its frags
  STG(0, 0);
  STG(1, 1);
  asm volatile("s_waitcnt vmcnt(3)" ::: "memory");  // own STG(0) landed
  __builtin_amdgcn_s_barrier();                     // all waves' STG(0) landed
  __builtin_amdgcn_sched_barrier(0);
  {
    const char* ab0 = lds + wm * 4096 + pbase;
    const char* bb0 = lds + 16384 + wn * 4096 + pbase;
#pragma unroll
    for (int i = 0; i < 4; ++i) af[i] = *(const bf16x8*)(ab0 + i * 1024);
#pragma unroll
    for (int j = 0; j < 4; ++j) bs0[j] = *(const bf16x8*)(bb0 + j * 1024);
  }

#pragma unroll
  for (int sp = 0; sp < NKT / 2; ++sp) {
    STEP(2 * sp, bs0, bs1);
    STEP(2 * sp + 1, bs1, bs0);
  }
  __syncthreads();  // all waves done with LDS; reusable for epilogue

  // ---- epilogue: LDS-shuffled coalesced writeout (R4-verified) ----
  if (OUT_BF16) {
    unsigned short* tile = (unsigned short*)lds;  // 256 x 128 bf16 = 64 KiB
#pragma unroll
    for (int fi = 0; fi < 4; ++fi) {
#pragma unroll
      for (int cj = 0; cj < 4; ++cj) {
        int col = wn * 64 + cj * 16 + lrow;
        float bv = bias[bn0 + col];
#pragma unroll
        for (int r = 0; r < 4; ++r) {
          int row = wm * 64 + fi * 16 + kg * 4 + r;
          int sc = (((col >> 3) ^ (row & 7)) << 3) | (col & 7);
          tile[row * 128 + sc] = f2bf(acc[fi][cj][r] + bv);
        }
      }
    }
    __syncthreads();
#pragma unroll
    for (int it = 0; it < 8; ++it) {
      int id = it * 512 + tid;
      int row = id >> 4;  // 0..255 ; 16 x 16B chunks/row
      int c = id & 15;
      uint4 v = *(const uint4*)(lds + row * 256 + ((c ^ (row & 7)) << 4));
      *(uint4*)((unsigned short*)C + (size_t)(bm0 + row) * N + bn0 + c * 8) = v;
    }
  } else {
    float* tilef = (float*)lds;  // 128 x 128 f32 = 64 KiB per pass
#pragma unroll
    for (int pass = 0; pass < 2; ++pass) {
      if ((wm >> 1) == pass) {
#pragma unroll
        for (int fi = 0; fi < 4; ++fi) {
#pragma unroll
          for (int cj = 0; cj < 4; ++cj) {
            int col = wn * 64 + cj * 16 + lrow;
            float bv = bias[bn0 + col];
#pragma unroll
            for (int r = 0; r < 4; ++r) {
              int row = (wm & 1) * 64 + fi * 16 + kg * 4 + r;  // 0..127
              int sc = (((col >> 2) ^ (row & 7)) << 2) | (col & 3);
              tilef[row * 128 + sc] = acc[fi][cj][r] + bv;
            }
          }
        }
      }
      __syncthreads();
#pragma unroll
      for (int it = 0; it < 8; ++it) {
        int id = it * 512 + tid;
        int row = id >> 5;  // 0..127 ; 32 x 16B chunks/row
        int c = id & 31;
        uint4 v = *(const uint4*)(lds + row * 512 + ((c ^ (row & 7)) << 4));
        *(uint4*)((float*)C + (size_t)(bm0 + pass * 128 + row) * N + bn0 + c * 4) = v;
      }
      __syncthreads();
    }
  }
}

// ---------------- per-token attention, 1 token per wave ----------------
__global__ __launch_bounds__(256) void attn_tok(const __hip_bfloat16* __restrict__ qkv,
                                                __hip_bfloat16* __restrict__ outp,
                                                int ntok, int npb) {
  const int wv = threadIdx.x >> 6;
  const int ln = threadIdx.x & 63;
  const int t = blockIdx.x * 4 + wv;
  if (t >= ntok) return;
  const int m = ln & 7;

  const __hip_bfloat16* row = qkv + (size_t)t * 1536;
  uint4 qr = *(const uint4*)(row + ln * 8);
  uint4 kr = *(const uint4*)(row + 512 + ln * 8);
  uint4 vr = *(const uint4*)(row + 1024 + ln * 8);

  float qf[8];
  unpk2(qr.x, qf[0], qf[1]);
  unpk2(qr.y, qf[2], qf[3]);
  unpk2(qr.z, qf[4], qf[5]);
  unpk2(qr.w, qf[6], qf[7]);
  unsigned kw[4] = {kr.x, kr.y, kr.z, kr.w};
  unsigned vw[4] = {vr.x, vr.y, vr.z, vr.w};

  float dt[8];
#pragma unroll
  for (int g = 0; g < 8; ++g) {
    int src = g * 8 + m;
    float s = 0.f;
#pragma unroll
    for (int j4 = 0; j4 < 4; ++j4) {
      unsigned kk = __shfl(kw[j4], src, 64);
      float a, b;
      unpk2(kk, a, b);
      s += qf[j4 * 2] * a + qf[j4 * 2 + 1] * b;
    }
    s += __shfl_xor(s, 1, 64);
    s += __shfl_xor(s, 2, 64);
    s += __shfl_xor(s, 4, 64);
    dt[g] = s;
  }

  float mx = -1e30f;
#pragma unroll
  for (int g = 0; g < 8; ++g) {
    dt[g] = fminf(fmaxf(dt[g] * 0.125f, -50.f), 50.f);
    mx = fmaxf(mx, dt[g]);
  }
  float p[8], ssum = 0.f;
#pragma unroll
  for (int g = 0; g < 8; ++g) {
    p[g] = __expf(dt[g] - mx);
    ssum += p[g];
  }
  float inv = 1.f / ssum;

  float o[8] = {0, 0, 0, 0, 0, 0, 0, 0};
#pragma unroll
  for (int g = 0; g < 8; ++g) {
    int src = g * 8 + m;
    float ag = p[g] * inv;
#pragma unroll
    for (int j4 = 0; j4 < 4; ++j4) {
      unsigned vv = __shfl(vw[j4], src, 64);
      float a, b;
      unpk2(vv, a, b);
      o[j4 * 2] += ag * a;
      o[j4 * 2 + 1] += ag * b;
    }
  }

  const int h = ln >> 3;
  const int b = t / npb, n = t % npb;
  size_t dst = (size_t)b * npb * 512 + (size_t)(h * (npb >> 3) + (n >> 3)) * 512 +
               (size_t)((n & 7) * 64 + m * 8);
  uint4 ov;
  ov.x = pk2(o[0], o[1]);
  ov.y = pk2(o[2], o[3]);
  ov.z = pk2(o[4], o[5]);
  ov.w = pk2(o[6], o[7]);
  *(uint4*)(outp + dst) = ov;
}

// ---------------- launch ----------------
extern "C" void kernel_launch(void* const* d_in, const int* in_sizes, int n_in,
                              void* d_out, int out_size, void* d_ws, size_t ws_size,
                              hipStream_t stream) {
  const float* x = (const float*)d_in[0];
  const float* w_qkv = (const float*)d_in[1];
  const float* b_qkv = (const float*)d_in[2];
  const float* w_fc = (const float*)d_in[3];
  const float* b_fc = (const float*)d_in[4];
  float* out = (float*)d_out;

  const int M = 32768;
  const int Cc = 512, N3 = 1536;

  __hip_bfloat16* xb = (__hip_bfloat16*)d_ws;
  __hip_bfloat16* wqkvb = xb + (size_t)M * Cc;
  __hip_bfloat16* wfcb = wqkvb + (size_t)N3 * Cc;
  __hip_bfloat16* qkvb = wfcb + (size_t)Cc * Cc;
  __hip_bfloat16* attb = qkvb + (size_t)M * N3;

  cvt_all<<<8704, 256, 0, stream>>>(x, w_qkv, w_fc, (unsigned short*)xb,
                                    (unsigned short*)wqkvb, (unsigned short*)wfcb);

  gemmp<true, 512><<<(M / 256) * (N3 / 128), 512, 0, stream>>>(xb, wqkvb, b_qkv, qkvb, M, N3,
                                                               N3 / 128);
  attn_tok<<<M / 4, 256, 0, stream>>>(qkvb, attb, M, 8192);
  gemmp<false, 512><<<(M / 256) * (Cc / 128), 512, 0, stream>>>(attb, wfcb, b_fc, out, M, Cc,
                                                                Cc / 128);
}